// Round 1
// baseline (658.181 us; speedup 1.0000x reference)
//
#include <hip/hip_runtime.h>
#include <math.h>

#define BS 4096
#define C_CLS 16384
#define D 128

// ---------------- small kernels ----------------

__global__ void init_acc_kernel(float* acc) {
    if (threadIdx.x < 4) acc[threadIdx.x] = 0.0f;
}

__global__ __launch_bounds__(64) void normalize_rows(const float* __restrict__ in,
                                                     float* __restrict__ out) {
    int row = blockIdx.x;
    int lane = threadIdx.x;
    const float2* ip = (const float2*)(in + (size_t)row * D);
    float2 v = ip[lane];
    float ss = v.x * v.x + v.y * v.y;
#pragma unroll
    for (int off = 32; off; off >>= 1) ss += __shfl_xor(ss, off);
    float inv = 1.0f / sqrtf(ss);
    float2 o;
    o.x = v.x * inv;
    o.y = v.y * inv;
    ((float2*)(out + (size_t)row * D))[lane] = o;
}

__global__ void finalize_kernel(const float* __restrict__ acc, float* __restrict__ out) {
    out[0] = acc[0] / fmaxf(acc[1], 1.0f) + acc[2] / fmaxf(acc[3], 1.0f);
}

// ---------------- fused sim + masked-LSE kernel ----------------
// Computes, for RPB "columns" (proxy rows in NEG mode, batch indices j in POS
// mode), the masked logsumexp over all BS batch rows i, then softplus, then
// accumulates (sum, count) over nonzero entries into acc.
//
// NEG mode: value = dot(bnorm[i], pnorm[c]),         mask = labels[i] != c
//           w = 32*(v + 0.1),  ref = max of m (m = mask ? w : 0)
// POS mode: value = dot(bnorm[i], pnorm[labels[j]]), mask = labels[i] == labels[j]
//           w = -32*(v - 0.1), ref = min of m

template <int RPB, int TR, int TI, bool IS_POS>
__global__ __launch_bounds__(256) void lse_kernel(const float* __restrict__ bnorm,
                                                  const float* __restrict__ pnorm,
                                                  const int* __restrict__ labels,
                                                  float* __restrict__ acc) {
    constexpr int NTR = RPB / TR;   // thread-rows
    constexpr int NTI = 64 / TI;    // thread-cols (i within a 64-chunk)
    static_assert(NTR * NTI == 256, "bad tiling");
    constexpr int LD = D + 4;       // LDS pad (keeps float4 alignment, spreads banks)

    __shared__ float lds_p[RPB][LD];
    __shared__ float lds_b[64][LD];
    __shared__ int lds_lab[64];
    __shared__ int lds_rowlab[RPB];
    __shared__ float lds_state[RPB][NTI][3];

    const int tid = threadIdx.x;
    const int tr = tid % NTR;
    const int ti = tid / NTR;
    const int r0 = blockIdx.x * RPB;

    // stage this block's proxy rows into LDS (POS gathers via labels)
    for (int t = tid; t < RPB * (D / 4); t += 256) {
        int row = t / (D / 4);
        int c4 = t % (D / 4);
        int prow = IS_POS ? labels[r0 + row] : (r0 + row);
        float4 v = ((const float4*)(pnorm + (size_t)prow * D))[c4];
        *(float4*)&lds_p[row][c4 * 4] = v;
    }
    if (IS_POS && tid < RPB) lds_rowlab[tid] = labels[r0 + tid];

    // per-row online LSE state (per thread: covers its own i-subset)
    float mx[TR], mn[TR], sm[TR];
#pragma unroll
    for (int u = 0; u < TR; u++) {
        mx[u] = -INFINITY;
        mn[u] = INFINITY;
        sm[u] = 0.0f;
    }

    for (int i0 = 0; i0 < BS; i0 += 64) {
        __syncthreads();
        // stage 64 batch rows
        for (int t = tid; t < 64 * (D / 4); t += 256) {
            int row = t / (D / 4);
            int c4 = t % (D / 4);
            float4 v = ((const float4*)(bnorm + (size_t)(i0 + row) * D))[c4];
            *(float4*)&lds_b[row][c4 * 4] = v;
        }
        if (tid < 64) lds_lab[tid] = labels[i0 + tid];
        __syncthreads();

        // register-tiled dot products: TR proxy-rows x TI batch-rows
        float dacc[TR][TI];
#pragma unroll
        for (int u = 0; u < TR; u++)
#pragma unroll
            for (int v = 0; v < TI; v++) dacc[u][v] = 0.0f;

#pragma unroll
        for (int k = 0; k < D; k += 4) {
            float4 pa[TR], bb[TI];
#pragma unroll
            for (int u = 0; u < TR; u++) pa[u] = *(const float4*)&lds_p[u * NTR + tr][k];
#pragma unroll
            for (int v = 0; v < TI; v++) bb[v] = *(const float4*)&lds_b[ti * TI + v][k];
#pragma unroll
            for (int u = 0; u < TR; u++)
#pragma unroll
                for (int v = 0; v < TI; v++) {
                    dacc[u][v] = fmaf(pa[u].x, bb[v].x, dacc[u][v]);
                    dacc[u][v] = fmaf(pa[u].y, bb[v].y, dacc[u][v]);
                    dacc[u][v] = fmaf(pa[u].z, bb[v].z, dacc[u][v]);
                    dacc[u][v] = fmaf(pa[u].w, bb[v].w, dacc[u][v]);
                }
        }

        // fold into online LSE state
#pragma unroll
        for (int u = 0; u < TR; u++) {
            int rl = u * NTR + tr;
            int negc = r0 + rl;
            int plab = IS_POS ? lds_rowlab[rl] : 0;
#pragma unroll
            for (int v = 0; v < TI; v++) {
                int li = lds_lab[ti * TI + v];
                bool mask = IS_POS ? (li == plab) : (li != negc);
                float d = dacc[u][v];
                float w = IS_POS ? (-32.0f * (d - 0.1f)) : (32.0f * (d + 0.1f));
                float m = mask ? w : 0.0f;
                if (IS_POS) {
                    // ref = running min of m
                    float nm = fminf(mn[u], m);
                    float rs = (sm[u] == 0.0f) ? 0.0f : sm[u] * __expf(mn[u] - nm);
                    sm[u] = rs + (mask ? __expf(w - nm) : 0.0f);
                    mn[u] = nm;
                    mx[u] = fmaxf(mx[u], m);
                } else {
                    // ref = running max of m
                    float nm = fmaxf(mx[u], m);
                    float rs = (sm[u] == 0.0f) ? 0.0f : sm[u] * __expf(mx[u] - nm);
                    sm[u] = rs + (mask ? __expf(w - nm) : 0.0f);
                    mx[u] = nm;
                    mn[u] = fminf(mn[u], m);
                }
            }
        }
    }

    __syncthreads();
#pragma unroll
    for (int u = 0; u < TR; u++) {
        int rl = u * NTR + tr;
        lds_state[rl][ti][0] = mx[u];
        lds_state[rl][ti][1] = mn[u];
        lds_state[rl][ti][2] = sm[u];
    }
    __syncthreads();

    float add = 0.0f, cntv = 0.0f;
    if (tid < RPB) {
        float gmx = -INFINITY, gmn = INFINITY;
#pragma unroll 4
        for (int k = 0; k < NTI; k++) {
            gmx = fmaxf(gmx, lds_state[tid][k][0]);
            gmn = fminf(gmn, lds_state[tid][k][1]);
        }
        float ref = IS_POS ? gmn : gmx;
        float s = 0.0f;
#pragma unroll 4
        for (int k = 0; k < NTI; k++) {
            float rk = IS_POS ? lds_state[tid][k][1] : lds_state[tid][k][0];
            float sk = lds_state[tid][k][2];
            if (sk != 0.0f) s += sk * __expf(rk - ref);
        }
        bool nz = (gmx + gmn) != 0.0f;
        float lse = logf(nz ? s : 1.0f) + ref;
        float sp = (lse > 0.0f) ? (lse + log1pf(__expf(-lse))) : log1pf(__expf(lse));
        add = nz ? sp : 0.0f;
        cntv = nz ? 1.0f : 0.0f;
    }
    // lanes >= RPB hold zeros; reduce wave 0 and emit one atomic pair per block
    if (tid < 64) {
#pragma unroll
        for (int off = 32; off; off >>= 1) {
            add += __shfl_xor(add, off);
            cntv += __shfl_xor(cntv, off);
        }
        if (tid == 0) {
            atomicAdd(&acc[IS_POS ? 0 : 2], add);
            atomicAdd(&acc[IS_POS ? 1 : 3], cntv);
        }
    }
}

// ---------------- launch ----------------

extern "C" void kernel_launch(void* const* d_in, const int* in_sizes, int n_in,
                              void* d_out, int out_size, void* d_ws, size_t ws_size,
                              hipStream_t stream) {
    const float* batch = (const float*)d_in[0];
    const float* proxies = (const float*)d_in[1];
    const int* labels = (const int*)d_in[2];
    float* out = (float*)d_out;

    float* acc = (float*)d_ws;                              // 4 floats
    float* bnorm = (float*)((char*)d_ws + 1024);            // [BS][D]
    float* pnorm = bnorm + (size_t)BS * D;                  // [C][D]

    init_acc_kernel<<<1, 64, 0, stream>>>(acc);
    normalize_rows<<<BS, 64, 0, stream>>>(batch, bnorm);
    normalize_rows<<<C_CLS, 64, 0, stream>>>(proxies, pnorm);

    // POS: 4096 columns j, 16 per block -> 256 blocks
    lse_kernel<16, 1, 4, true><<<BS / 16, 256, 0, stream>>>(bnorm, pnorm, labels, acc);
    // NEG: 16384 proxy columns, 64 per block -> 256 blocks
    lse_kernel<64, 4, 4, false><<<C_CLS / 64, 256, 0, stream>>>(bnorm, pnorm, labels, acc);

    finalize_kernel<<<1, 1, 0, stream>>>(acc, out);
}

// Round 2
// 90.371 us; speedup vs baseline: 7.2831x; 7.2831x over previous
//
#include <hip/hip_runtime.h>
#include <math.h>

#define BS 4096
#define C_CLS 16384
#define D 128

#define NS_NEG 8
#define NS_POS 16
#define CH 64

typedef __attribute__((ext_vector_type(8))) short short8;
typedef __attribute__((ext_vector_type(4))) float f32x4;

__device__ inline unsigned short f2bf(float f) {
    unsigned u = __float_as_uint(f);
    u += 0x7FFF + ((u >> 16) & 1);  // RNE
    return (unsigned short)(u >> 16);
}

// ---------------- small kernels ----------------

__global__ void init_acc_kernel(float* acc) {
    if (threadIdx.x < 4) acc[threadIdx.x] = 0.0f;
}

// 4 rows per block (one wave per row), fp32 in -> normalized bf16 out
__global__ __launch_bounds__(256) void normalize_bf16(const float* __restrict__ in,
                                                      short* __restrict__ out) {
    int row = blockIdx.x * 4 + (threadIdx.x >> 6);
    int lane = threadIdx.x & 63;
    float2 v = ((const float2*)(in + (size_t)row * D))[lane];
    float ss = v.x * v.x + v.y * v.y;
#pragma unroll
    for (int off = 32; off; off >>= 1) ss += __shfl_xor(ss, off);
    float inv = rsqrtf(ss);
    ushort2 o;
    o.x = f2bf(v.x * inv);
    o.y = f2bf(v.y * inv);
    ((ushort2*)(out + (size_t)row * D))[lane] = o;
}

__global__ void combine_kernel(const float* __restrict__ acc, float* __restrict__ out) {
    out[0] = acc[0] / fmaxf(acc[1], 1.0f) + acc[2] / fmaxf(acc[3], 1.0f);
}

// ---------------- NEG: masked LSE over batch dim per proxy ----------------
// w = 32*sim + 3.2, ref fixed = 36. Partials (mx, mn, s36) per (proxy, split).

__global__ __launch_bounds__(256) void neg_lse(const short* __restrict__ pbf,
                                               const short* __restrict__ bbf,
                                               const int* __restrict__ labels,
                                               float* __restrict__ negS,
                                               float* __restrict__ negMx,
                                               float* __restrict__ negMn) {
    __shared__ short lds_b[CH][136];
    __shared__ int lds_lab[CH];

    const int tid = threadIdx.x;
    const int w = tid >> 6;
    const int lane = tid & 63;
    const int l16 = lane & 15;
    const int g = lane >> 4;
    const int tile = blockIdx.x & 255;  // C/64 tiles
    const int sp = blockIdx.x >> 8;     // 0..NS_NEG-1
    const int r0 = tile * 64 + w * 16;

    // A fragment: proxies, row = r0 + l16, fixed for whole kernel
    short8 a[4];
    {
        const short* ap = pbf + (size_t)(r0 + l16) * D + g * 8;
#pragma unroll
        for (int kk = 0; kk < 4; kk++) a[kk] = *(const short8*)(ap + kk * 32);
    }
    const int cbase = r0 + g * 4;  // C/D row base for this lane

    float mx[4], mn[4], s[4];
#pragma unroll
    for (int r = 0; r < 4; r++) { mx[r] = -INFINITY; mn[r] = INFINITY; s[r] = 0.0f; }

    const int ibeg = sp * (BS / NS_NEG);
    for (int i0 = ibeg; i0 < ibeg + BS / NS_NEG; i0 += CH) {
        __syncthreads();
        for (int t = tid; t < CH * 16; t += 256) {
            int row = t >> 4, c8 = t & 15;
            *(short8*)&lds_b[row][c8 * 8] =
                *(const short8*)(bbf + (size_t)(i0 + row) * D + c8 * 8);
        }
        if (tid < CH) lds_lab[tid] = labels[i0 + tid];
        __syncthreads();

#pragma unroll
        for (int n0 = 0; n0 < CH; n0 += 16) {
            short8 b[4];
#pragma unroll
            for (int kk = 0; kk < 4; kk++)
                b[kk] = *(const short8*)&lds_b[n0 + l16][kk * 32 + g * 8];
            f32x4 acc = {0.0f, 0.0f, 0.0f, 0.0f};
#pragma unroll
            for (int kk = 0; kk < 4; kk++)
                acc = __builtin_amdgcn_mfma_f32_16x16x32_bf16(a[kk], b[kk], acc, 0, 0, 0);
            const int li = lds_lab[n0 + l16];
#pragma unroll
            for (int r = 0; r < 4; r++) {
                float d = acc[r];
                bool mk = (li != cbase + r);
                float wv = fmaf(d, 32.0f, 3.2f);
                float m = mk ? wv : 0.0f;
                mx[r] = fmaxf(mx[r], m);
                mn[r] = fminf(mn[r], m);
                float e = __expf(wv - 36.0f);
                s[r] += mk ? e : 0.0f;
            }
        }
    }

    // reduce over the 16 col-lanes (same output row group)
#pragma unroll
    for (int off = 1; off < 16; off <<= 1) {
#pragma unroll
        for (int r = 0; r < 4; r++) {
            mx[r] = fmaxf(mx[r], __shfl_xor(mx[r], off));
            mn[r] = fminf(mn[r], __shfl_xor(mn[r], off));
            s[r] += __shfl_xor(s[r], off);
        }
    }
    if (l16 == 0) {
#pragma unroll
        for (int r = 0; r < 4; r++) {
            int idx = (cbase + r) * NS_NEG + sp;
            negS[idx] = s[r];
            negMx[idx] = mx[r];
            negMn[idx] = mn[r];
        }
    }
}

// ---------------- POS: masked LSE over batch dim per batch col j ----------------
// w = -32*sim + 3.2, ref fixed = 0. Partials per (j, split).

__global__ __launch_bounds__(256) void pos_lse(const short* __restrict__ pbf,
                                               const short* __restrict__ bbf,
                                               const int* __restrict__ labels,
                                               float* __restrict__ posS,
                                               float* __restrict__ posMx,
                                               float* __restrict__ posMn) {
    __shared__ short lds_b[CH][136];
    __shared__ int lds_lab[CH];

    const int tid = threadIdx.x;
    const int w = tid >> 6;
    const int lane = tid & 63;
    const int l16 = lane & 15;
    const int g = lane >> 4;
    const int tile = blockIdx.x & 63;  // BS/64 tiles
    const int sp = blockIdx.x >> 6;    // 0..NS_POS-1
    const int j0 = tile * 64 + w * 16;
    const int jcol = j0 + l16;
    const int labj = labels[jcol];

    // B fragment: gathered proxy row labels[jcol], fixed
    short8 b[4];
    {
        const short* bp = pbf + (size_t)labj * D + g * 8;
#pragma unroll
        for (int kk = 0; kk < 4; kk++) b[kk] = *(const short8*)(bp + kk * 32);
    }

    float mx = -INFINITY, mn = INFINITY, s = 0.0f;

    const int ibeg = sp * (BS / NS_POS);
    for (int i0 = ibeg; i0 < ibeg + BS / NS_POS; i0 += CH) {
        __syncthreads();
        for (int t = tid; t < CH * 16; t += 256) {
            int row = t >> 4, c8 = t & 15;
            *(short8*)&lds_b[row][c8 * 8] =
                *(const short8*)(bbf + (size_t)(i0 + row) * D + c8 * 8);
        }
        if (tid < CH) lds_lab[tid] = labels[i0 + tid];
        __syncthreads();

#pragma unroll
        for (int n0 = 0; n0 < CH; n0 += 16) {
            short8 a[4];
#pragma unroll
            for (int kk = 0; kk < 4; kk++)
                a[kk] = *(const short8*)&lds_b[n0 + l16][kk * 32 + g * 8];
            f32x4 acc = {0.0f, 0.0f, 0.0f, 0.0f};
#pragma unroll
            for (int kk = 0; kk < 4; kk++)
                acc = __builtin_amdgcn_mfma_f32_16x16x32_bf16(a[kk], b[kk], acc, 0, 0, 0);
#pragma unroll
            for (int r = 0; r < 4; r++) {
                const int li = lds_lab[n0 + g * 4 + r];  // element row = i
                float d = acc[r];
                bool mk = (li == labj);
                float wv = fmaf(d, -32.0f, 3.2f);
                float m = mk ? wv : 0.0f;
                mx = fmaxf(mx, m);
                mn = fminf(mn, m);
                float e = __expf(wv);
                s += mk ? e : 0.0f;
            }
        }
    }

    // reduce over the 4 row-group lanes holding the same col (xor 16, 32)
#pragma unroll
    for (int off = 16; off < 64; off <<= 1) {
        mx = fmaxf(mx, __shfl_xor(mx, off));
        mn = fminf(mn, __shfl_xor(mn, off));
        s += __shfl_xor(s, off);
    }
    if (lane < 16) {
        int idx = jcol * NS_POS + sp;
        posS[idx] = s;
        posMx[idx] = mx;
        posMn[idx] = mn;
    }
}

// ---------------- final per-entry reduce + softplus + mean accumulation ----------------

__global__ __launch_bounds__(256) void final_reduce(const float* __restrict__ S,
                                                    const float* __restrict__ Mx,
                                                    const float* __restrict__ Mn,
                                                    int n, int ns, float ref_add,
                                                    float* __restrict__ acc, int slot) {
    int i = blockIdx.x * 256 + threadIdx.x;
    float add = 0.0f, cnt = 0.0f;
    if (i < n) {
        float mx = -INFINITY, mn = INFINITY, s = 0.0f;
        for (int p = 0; p < ns; p++) {
            mx = fmaxf(mx, Mx[i * ns + p]);
            mn = fminf(mn, Mn[i * ns + p]);
            s += S[i * ns + p];
        }
        bool nz = (mx + mn) != 0.0f;
        if (nz) {
            float lse = logf(s) + ref_add;
            add = fmaxf(lse, 0.0f) + log1pf(expf(-fabsf(lse)));  // softplus
            cnt = 1.0f;
        }
    }
#pragma unroll
    for (int off = 32; off; off >>= 1) {
        add += __shfl_xor(add, off);
        cnt += __shfl_xor(cnt, off);
    }
    if ((threadIdx.x & 63) == 0) {
        atomicAdd(&acc[slot], add);
        atomicAdd(&acc[slot + 1], cnt);
    }
}

// ---------------- launch ----------------

extern "C" void kernel_launch(void* const* d_in, const int* in_sizes, int n_in,
                              void* d_out, int out_size, void* d_ws, size_t ws_size,
                              hipStream_t stream) {
    const float* batch = (const float*)d_in[0];
    const float* proxies = (const float*)d_in[1];
    const int* labels = (const int*)d_in[2];
    float* out = (float*)d_out;

    char* ws = (char*)d_ws;
    float* acc = (float*)ws;                                   // 4 floats
    short* bbf = (short*)(ws + 256);                           // [BS][D] bf16
    short* pbf = (short*)(ws + 256 + (size_t)BS * D * 2);      // [C][D] bf16
    float* negp = (float*)(ws + 256 + (size_t)(BS + C_CLS) * D * 2);
    float* negS = negp;
    float* negMx = negp + (size_t)C_CLS * NS_NEG;
    float* negMn = negp + (size_t)2 * C_CLS * NS_NEG;
    float* posp = negp + (size_t)3 * C_CLS * NS_NEG;
    float* posS = posp;
    float* posMx = posp + (size_t)BS * NS_POS;
    float* posMn = posp + (size_t)2 * BS * NS_POS;

    init_acc_kernel<<<1, 64, 0, stream>>>(acc);
    normalize_bf16<<<BS / 4, 256, 0, stream>>>(batch, bbf);
    normalize_bf16<<<C_CLS / 4, 256, 0, stream>>>(proxies, pbf);

    neg_lse<<<(C_CLS / 64) * NS_NEG, 256, 0, stream>>>(pbf, bbf, labels, negS, negMx, negMn);
    pos_lse<<<(BS / 64) * NS_POS, 256, 0, stream>>>(pbf, bbf, labels, posS, posMx, posMn);

    final_reduce<<<C_CLS / 256, 256, 0, stream>>>(negS, negMx, negMn, C_CLS, NS_NEG, 36.0f, acc, 2);
    final_reduce<<<BS / 256, 256, 0, stream>>>(posS, posMx, posMn, BS, NS_POS, 0.0f, acc, 0);

    combine_kernel<<<1, 1, 0, stream>>>(acc, out);
}